// Round 21
// baseline (251.728 us; speedup 1.0000x reference)
//
#include <hip/hip_runtime.h>
#include <hip/hip_bf16.h>
#include <math.h>

// InformationPlane R21 (= R20 + cached copy-loads): the x->out copy used
// nontemporal LOADS which bypass L3 -- but x (134MB) is still L3-resident
// from k_prep (x+xbf=198MB < 256MB L3). gemm2 FETCH=143MB ~= full HBM
// re-read confirms the bypass. Now: normal loads (L3 hits), NT stores kept
// (d_out never re-read; don't evict xbf). Everything else = R20.

#define NBATCH 8
#define MBS    512
#define DXX    8192
#define DII    3072
#define NSIG   50
#define NN     262144                 // 512*512
#define NTOT   ((size_t)33554432)     // 4096*8192
#define NGEMM  576

// scal (double) indices
#define I_SUMD  0    // 8
#define I_KYF   8    // 8
#define I_SIGMA 24   // 8
#define I_ENT   32   // 40 (b*5+m)
#define I_NUM   96   // 8*50
#define I_DEN   512  // 8*50 -> 912
#define I_AX2   912  // 8  sum ax^2
#define I_A2    920  // 8  sum a^2
#define I_JX2   928  // 8  sum (ax*a)^2
#define I_JY2   936  // 8  sum (a*ay)^2 -> ends 944

typedef __attribute__((ext_vector_type(8))) short bf16x8;
typedef __attribute__((ext_vector_type(4))) float f32x4;

__device__ __forceinline__ size_t slotOf(int b, int m) {
  return ((size_t)(b * 5 + m)) * (size_t)NN;
}

__device__ __forceinline__ short f2b(float f) {
  __hip_bfloat16 h = __float2bfloat16(f);
  return *(short*)&h;
}

__device__ __forceinline__ ushort4 cvt4(float4 a) {
  ushort4 v;
  v.x = (ushort)f2b(a.x); v.y = (ushort)f2b(a.y);
  v.z = (ushort)f2b(a.z); v.w = (ushort)f2b(a.w);
  return v;
}

__device__ __forceinline__ double n4(float4 a) {
  return (double)a.x * a.x + (double)a.y * a.y + (double)a.z * a.z + (double)a.w * a.w;
}

// ---------------- copy x -> out (small-ws path only) ----------------
__global__ void k_copy(const float4* __restrict__ src, float4* __restrict__ dst, size_t n4) {
  size_t i = (size_t)blockIdx.x * blockDim.x + threadIdx.x;
  size_t stride = (size_t)gridDim.x * blockDim.x;
  for (; i < n4; i += stride) dst[i] = src[i];
}

// ---------------- fused prep: x-rows | inp-rows | Ky ----------------
__global__ __launch_bounds__(256) void k_prep(
    const float4* __restrict__ x4,
    const float* __restrict__ inp, const float* __restrict__ lab,
    ushort* __restrict__ xbf, ushort* __restrict__ inpbf,
    float* __restrict__ nrmx, float* __restrict__ nrmi,
    float* __restrict__ eig, double* __restrict__ scal)
{
  __shared__ double red[256];
  int bid = blockIdx.x, t = threadIdx.x;

  if (bid < 4096) {                       // ---- x rows ----
    int row = bid;
    const float4* p4 = x4 + (size_t)row * 2048;
    float4 f0 = p4[t];
    float4 f1 = p4[t + 256];
    float4 f2 = p4[t + 512];
    float4 f3 = p4[t + 768];
    float4 f4 = p4[t + 1024];
    float4 f5 = p4[t + 1280];
    float4 f6 = p4[t + 1536];
    float4 f7 = p4[t + 1792];
    __builtin_amdgcn_sched_barrier(0);
    ushort4* o4 = (ushort4*)(xbf + (size_t)row * 8192);
    o4[t]        = cvt4(f0);
    o4[t + 256]  = cvt4(f1);
    o4[t + 512]  = cvt4(f2);
    o4[t + 768]  = cvt4(f3);
    o4[t + 1024] = cvt4(f4);
    o4[t + 1280] = cvt4(f5);
    o4[t + 1536] = cvt4(f6);
    o4[t + 1792] = cvt4(f7);
    double s = n4(f0) + n4(f1) + n4(f2) + n4(f3) + n4(f4) + n4(f5) + n4(f6) + n4(f7);
    red[t] = s; __syncthreads();
    for (int o2 = 128; o2 > 0; o2 >>= 1) {
      if (t < o2) red[t] += red[t + o2];
      __syncthreads();
    }
    if (t == 0) nrmx[row] = (float)red[0];
    return;
  }

  if (bid < 6144) {                       // ---- inp: 2 rows per block ----
    int p = bid - 4096;                   // row pair
    const float4* src4 = (const float4*)inp + (size_t)p * 768;
    ushort4* dst4 = (ushort4*)inpbf + (size_t)p * 768;
    float4 g0 = src4[t];
    float4 g1 = src4[t + 256];
    float4 g2 = src4[t + 512];
    __builtin_amdgcn_sched_barrier(0);
    dst4[t]       = cvt4(g0);
    dst4[t + 256] = cvt4(g1);
    dst4[t + 512] = cvt4(g2);
    double s0 = n4(g0), s1 = n4(g2);
    double sm = n4(g1);
    if (t < 128) s0 += sm; else s1 += sm;
    red[t] = s0; __syncthreads();
    for (int o = 128; o > 0; o >>= 1) { if (t < o) red[t] += red[t + o]; __syncthreads(); }
    if (t == 0) nrmi[2 * p] = (float)red[0];
    __syncthreads();
    red[t] = s1; __syncthreads();
    for (int o = 128; o > 0; o >>= 1) { if (t < o) red[t] += red[t + o]; __syncthreads(); }
    if (t == 0) nrmi[2 * p + 1] = (float)red[0];
    return;
  }

  // ---- Ky ----
  int idx = bid - 6144;                   // 0..2047
  int b = idx >> 8, xb = idx & 255;
  int e0 = xb * 1024 + t * 4;
  int i = e0 >> 9;
  const float* L = lab + (size_t)b * MBS * 10;
  float4 out;
  double s = 0.0;
#pragma unroll
  for (int u = 0; u < 4; u++) {
    int j = (e0 & 511) + u;
    float d2 = 0.0f;
#pragma unroll
    for (int d = 0; d < 10; d++) { float dd = L[i * 10 + d] - L[j * 10 + d]; d2 += dd * dd; }
    float ky = __expf(-d2 * 100.0f);
    ((float*)&out)[u] = ky * (1.0f / 512.0f);
    s += (double)ky * ky;
  }
  *(float4*)&eig[slotOf(b, 2) + e0] = out;
  red[t] = s; __syncthreads();
  for (int o = 128; o > 0; o >>= 1) { if (t < o) red[t] += red[t + o]; __syncthreads(); }
  if (t == 0) atomicAdd(&scal[I_KYF + b], red[0]);
}

// ---------------- symmetric bf16-MFMA pdist2 GEMM (BK=128) + overlapped copy --
#define LSTR2 136   // ushorts per LDS row (272B: 16B-aligned, bank-shifted)
#define LGKM0_BAR                                                             \
  do {                                                                        \
    asm volatile("s_waitcnt lgkmcnt(0)" ::: "memory");                        \
    __builtin_amdgcn_s_barrier();                                             \
    __builtin_amdgcn_sched_barrier(0);                                        \
  } while (0)

#define LOAD_SET(A0, A1, A2, A3, B0, B1, B2, B3, K0)                          \
  do {                                                                        \
    A0 = *(const bf16x8*)&srcA0[K0];                                          \
    A1 = *(const bf16x8*)&srcA1[K0];                                          \
    A2 = *(const bf16x8*)&srcA2[K0];                                          \
    A3 = *(const bf16x8*)&srcA3[K0];                                          \
    B0 = *(const bf16x8*)&srcB0[K0];                                          \
    B1 = *(const bf16x8*)&srcB1[K0];                                          \
    B2 = *(const bf16x8*)&srcB2[K0];                                          \
    B3 = *(const bf16x8*)&srcB3[K0];                                          \
  } while (0)

#define WRITE_LDS(BUF, A0, A1, A2, A3, B0, B1, B2, B3)                        \
  do {                                                                        \
    *(bf16x8*)&As[BUF][rr2 * LSTR2 + cc2] = A0;                               \
    *(bf16x8*)&As[BUF][(16 + rr2) * LSTR2 + cc2] = A1;                        \
    *(bf16x8*)&As[BUF][(32 + rr2) * LSTR2 + cc2] = A2;                        \
    *(bf16x8*)&As[BUF][(48 + rr2) * LSTR2 + cc2] = A3;                        \
    *(bf16x8*)&Bs[BUF][rr2 * LSTR2 + cc2] = B0;                               \
    *(bf16x8*)&Bs[BUF][(16 + rr2) * LSTR2 + cc2] = B1;                        \
    *(bf16x8*)&Bs[BUF][(32 + rr2) * LSTR2 + cc2] = B2;                        \
    *(bf16x8*)&Bs[BUF][(48 + rr2) * LSTR2 + cc2] = B3;                        \
  } while (0)

#define MFMA_PHASE(BUF)                                                       \
  do {                                                                        \
    __builtin_amdgcn_s_setprio(1);                                            \
    _Pragma("unroll")                                                         \
    for (int ks = 0; ks < 4; ks++) {                                          \
      bf16x8 af0 = *(const bf16x8*)&As[BUF][(wr + l15) * LSTR2 + ks * 32 + l4 * 8];          \
      bf16x8 af1 = *(const bf16x8*)&As[BUF][(wr + 16 + l15) * LSTR2 + ks * 32 + l4 * 8];     \
      bf16x8 bg0 = *(const bf16x8*)&Bs[BUF][(wc + l15) * LSTR2 + ks * 32 + l4 * 8];          \
      bf16x8 bg1 = *(const bf16x8*)&Bs[BUF][(wc + 16 + l15) * LSTR2 + ks * 32 + l4 * 8];     \
      acc00 = __builtin_amdgcn_mfma_f32_16x16x32_bf16(af0, bg0, acc00, 0, 0, 0);             \
      acc01 = __builtin_amdgcn_mfma_f32_16x16x32_bf16(af0, bg1, acc01, 0, 0, 0);             \
      acc10 = __builtin_amdgcn_mfma_f32_16x16x32_bf16(af1, bg0, acc10, 0, 0, 0);             \
      acc11 = __builtin_amdgcn_mfma_f32_16x16x32_bf16(af1, bg1, acc11, 0, 0, 0);             \
    }                                                                         \
    __builtin_amdgcn_s_setprio(0);                                            \
  } while (0)

__global__ __launch_bounds__(256) void k_gemm2(
    const ushort* __restrict__ xbf, const ushort* __restrict__ inpbf,
    const float* __restrict__ nrmx, const float* __restrict__ nrmi,
    float* __restrict__ eig, double* __restrict__ scal,
    unsigned long long* __restrict__ cnt,
    const f32x4* __restrict__ xsrc, f32x4* __restrict__ xdst, int inter)
{
  int id = blockIdx.x;
  int tid = threadIdx.x;

  int gid;
  if (inter) {
    int g = id / 41, r = id % 41;       // grid 2624 = 41*64
    if (r >= 9) {                       // ---- overlapped x->out copy ----
      size_t base = (size_t)(g * 32 + (r - 9)) * 4096 + tid;   // float4 units
#pragma unroll
      for (int h = 0; h < 2; h++) {
        size_t o = base + (size_t)h * 2048;
        f32x4 c0 = xsrc[o];              // cached loads: x is L3-resident
        f32x4 c1 = xsrc[o + 256];
        f32x4 c2 = xsrc[o + 512];
        f32x4 c3 = xsrc[o + 768];
        f32x4 c4 = xsrc[o + 1024];
        f32x4 c5 = xsrc[o + 1280];
        f32x4 c6 = xsrc[o + 1536];
        f32x4 c7 = xsrc[o + 1792];
        __builtin_amdgcn_sched_barrier(0);
        __builtin_nontemporal_store(c0, xdst + o);
        __builtin_nontemporal_store(c1, xdst + o + 256);
        __builtin_nontemporal_store(c2, xdst + o + 512);
        __builtin_nontemporal_store(c3, xdst + o + 768);
        __builtin_nontemporal_store(c4, xdst + o + 1024);
        __builtin_nontemporal_store(c5, xdst + o + 1280);
        __builtin_nontemporal_store(c6, xdst + o + 1536);
        __builtin_nontemporal_store(c7, xdst + o + 1792);
      }
      return;
    }
    gid = g * 9 + r;                    // 0..575
  } else {
    gid = id;
  }

  int b = gid & 7;
  int tm = gid >> 3;                // 0..71
  int mode = (tm >= 36) ? 1 : 0;
  int t = tm - mode * 36;           // 0..35 lower-triangle tile
  int bx = 0;
#pragma unroll
  for (int r = 1; r < 8; r++) if (t >= (r * (r + 1)) / 2) bx = r;
  int by = t - (bx * (bx + 1)) / 2;
  bool diag = (bx == by);
  int D = mode ? DII : DXX;
  const ushort* src = (mode ? inpbf : xbf) + (size_t)b * MBS * D;
  const float* nb = (mode ? nrmi : nrmx) + b * MBS;
  int row0 = bx * 64, col0 = by * 64;

  __shared__ ushort As[2][64 * LSTR2];
  __shared__ ushort Bs[2][64 * LSTR2];
  __shared__ double redd[256];
  __shared__ unsigned redi[256];

  int lane = tid & 63, w = tid >> 6;
  int wr = (w >> 1) * 32, wc = (w & 1) * 32;
  int l15 = lane & 15, l4 = lane >> 4;

  f32x4 acc00 = {0.f, 0.f, 0.f, 0.f}, acc01 = {0.f, 0.f, 0.f, 0.f};
  f32x4 acc10 = {0.f, 0.f, 0.f, 0.f}, acc11 = {0.f, 0.f, 0.f, 0.f};

  int rr2 = tid >> 4;           // 0..15
  int cc2 = (tid & 15) * 8;     // 0..120

  const ushort* srcA0 = src + (size_t)(row0 + rr2) * D + cc2;
  const ushort* srcA1 = src + (size_t)(row0 + 16 + rr2) * D + cc2;
  const ushort* srcA2 = src + (size_t)(row0 + 32 + rr2) * D + cc2;
  const ushort* srcA3 = src + (size_t)(row0 + 48 + rr2) * D + cc2;
  const ushort* srcB0 = src + (size_t)(col0 + rr2) * D + cc2;
  const ushort* srcB1 = src + (size_t)(col0 + 16 + rr2) * D + cc2;
  const ushort* srcB2 = src + (size_t)(col0 + 32 + rr2) * D + cc2;
  const ushort* srcB3 = src + (size_t)(col0 + 48 + rr2) * D + cc2;

  bf16x8 pa0, pa1, pa2, pa3, pb0, pb1, pb2, pb3;   // even steps -> buf 0
  bf16x8 qa0, qa1, qa2, qa3, qb0, qb1, qb2, qb3;   // odd steps  -> buf 1

  LOAD_SET(pa0, pa1, pa2, pa3, pb0, pb1, pb2, pb3, 0);
  LOAD_SET(qa0, qa1, qa2, qa3, qb0, qb1, qb2, qb3, 128);

  int nk = D >> 7;              // 64 (x) or 24 (inp), both even
  for (int k = 0; k < nk; k += 2) {
    WRITE_LDS(0, pa0, pa1, pa2, pa3, pb0, pb1, pb2, pb3);
    if (k + 2 < nk) LOAD_SET(pa0, pa1, pa2, pa3, pb0, pb1, pb2, pb3, (k + 2) << 7);
    LGKM0_BAR;                  // LDS drain only; prefetch stays in flight
    MFMA_PHASE(0);
    WRITE_LDS(1, qa0, qa1, qa2, qa3, qb0, qb1, qb2, qb3);
    if (k + 3 < nk) LOAD_SET(qa0, qa1, qa2, qa3, qb0, qb1, qb2, qb3, (k + 3) << 7);
    LGKM0_BAR;
    MFMA_PHASE(1);
  }

  // epilogue (C/D layout: col=lane&15, row=(lane>>4)*4+v); mirror off-diag
  float* dst = eig + slotOf(b, mode ? 0 : 1);
  double lsum = 0.0; unsigned lcnt = 0;
#define EPI(ACC, M, N)                                                        \
  do {                                                                        \
    int gr = row0 + wr + (M) * 16 + l4 * 4;                                   \
    int gc = col0 + wc + (N) * 16 + l15;                                      \
    float nj = nb[gc];                                                        \
    _Pragma("unroll")                                                         \
    for (int v = 0; v < 4; v++) {                                             \
      int gi = gr + v;                                                        \
      float d2 = nb[gi] + nj - 2.0f * ACC[v];                                 \
      d2 = fmaxf(d2, 0.0f);                                                   \
      if (gi == gc) d2 = 0.0f;                                                \
      float val;                                                              \
      if (mode == 0) {                                                        \
        val = d2;                                                             \
        if (d2 > 0.0f) { lsum += (double)sqrtf(d2); lcnt++; }                 \
      } else {                                                                \
        val = __expf(-d2 * (1.0f / 64.0f)) * (1.0f / 512.0f);                 \
        lsum += (double)val * val;                                            \
      }                                                                       \
      dst[(size_t)gi * MBS + gc] = val;                                       \
      if (!diag) dst[(size_t)gc * MBS + gi] = val;                            \
    }                                                                         \
  } while (0)
  EPI(acc00, 0, 0); EPI(acc01, 0, 1); EPI(acc10, 1, 0); EPI(acc11, 1, 1);
#undef EPI

  if (!diag) { lsum *= 2.0; lcnt *= 2; }
  __syncthreads();
  redd[tid] = lsum; redi[tid] = lcnt; __syncthreads();
  for (int o = 128; o > 0; o >>= 1) {
    if (tid < o) { redd[tid] += redd[tid + o]; redi[tid] += redi[tid + o]; }
    __syncthreads();
  }
  if (tid == 0) {
    if (mode == 0) {
      atomicAdd(&scal[I_SUMD + b], redd[0]);
      atomicAdd(&cnt[b], (unsigned long long)redi[0]);
    } else {
      atomicAdd(&scal[I_AX2 + b], redd[0]);
    }
  }
}

// ---------------- sigma-search on 1/4 row subsample ----------------
#define SIG_DECL(I) float inv##I, ln##I = 0.0f, ld##I = 0.0f;
#define SIG_INIT(I) { float sg = md * (0.1f + 0.198f * (float)(g * 10 + I)); inv##I = 1.0f / (sg * sg); }
#define SIG_UP(I)   { float kk = __expf(fmaxf(-d2 * inv##I, -80.0f)); ln##I = fmaf(kk, ay, ln##I); ld##I = fmaf(kk, kk, ld##I); }
#define SIG_RED(I)                                                            \
  {                                                                           \
    float a = ln##I, d = ld##I;                                               \
    for (int o = 32; o > 0; o >>= 1) {                                        \
      a += __shfl_down(a, o, 64);                                             \
      d += __shfl_down(d, o, 64);                                             \
    }                                                                         \
    if (lane == 0) { wred[w][2 * (I)] = a; wred[w][2 * (I) + 1] = d; }        \
  }

__global__ __launch_bounds__(256) void k_loss(const float* __restrict__ eig,
                                              double* __restrict__ scal,
                                              const unsigned long long* __restrict__ cnt,
                                              unsigned* __restrict__ done) {
  int b = blockIdx.z, g = blockIdx.y;
  int lane = threadIdx.x & 63, w = threadIdx.x >> 6;
  __shared__ float wred[4][20];
  __shared__ int islast;
  double c = (double)cnt[b]; if (c < 1.0) c = 1.0;
  float md = (float)(scal[I_SUMD + b] / c);
  const float4* d2p = (const float4*)(eig + slotOf(b, 1));
  const float4* ayp = (const float4*)(eig + slotOf(b, 2));
  SIG_DECL(0) SIG_DECL(1) SIG_DECL(2) SIG_DECL(3) SIG_DECL(4)
  SIG_DECL(5) SIG_DECL(6) SIG_DECL(7) SIG_DECL(8) SIG_DECL(9)
  SIG_INIT(0) SIG_INIT(1) SIG_INIT(2) SIG_INIT(3) SIG_INIT(4)
  SIG_INIT(5) SIG_INIT(6) SIG_INIT(7) SIG_INIT(8) SIG_INIT(9)
  int rp = threadIdx.x >> 5;                 // 0..7: row slot in block
  int cc = threadIdx.x & 31;                 // 0..31: float4 within 128B group
  int row = (blockIdx.x * 8 + rp) * 4;       // actual matrix row (every 4th)
  int base = row * 128 + cc;                 // float4 index
#pragma unroll
  for (int l = 0; l < 4; l++) {
    float4 dv = d2p[base + l * 32];
    float4 av = ayp[base + l * 32];
#pragma unroll
    for (int u = 0; u < 4; u++) {
      float d2 = ((const float*)&dv)[u];
      float ay = ((const float*)&av)[u];
      SIG_UP(0) SIG_UP(1) SIG_UP(2) SIG_UP(3) SIG_UP(4)
      SIG_UP(5) SIG_UP(6) SIG_UP(7) SIG_UP(8) SIG_UP(9)
    }
  }
  SIG_RED(0) SIG_RED(1) SIG_RED(2) SIG_RED(3) SIG_RED(4)
  SIG_RED(5) SIG_RED(6) SIG_RED(7) SIG_RED(8) SIG_RED(9)
  __syncthreads();
  if (threadIdx.x < 20) {
    float v = wred[0][threadIdx.x] + wred[1][threadIdx.x]
            + wred[2][threadIdx.x] + wred[3][threadIdx.x];
    int i = threadIdx.x >> 1, isden = threadIdx.x & 1;
    if (isden) atomicAdd(&scal[I_DEN + b * NSIG + g * 10 + i], (double)v * 4.0);
    else       atomicAdd(&scal[I_NUM + b * NSIG + g * 10 + i], (double)v * 2048.0);  // *4*512
  }
  __syncthreads();
  if (threadIdx.x == 0) {
    unsigned r = atomicAdd(done, 1u);
    islast = (r == 16 * 5 * NBATCH - 1);
  }
  __syncthreads();
  if (!islast) return;
  __threadfence();

  if (threadIdx.x == 0) {
    double sigma = 0.0;
    for (int bb = 0; bb < NBATCH; bb++) {
      double cc2 = (double)cnt[bb]; if (cc2 < 1.0) cc2 = 1.0;
      double mdd = scal[I_SUMD + bb] / cc2;
      double kyf = sqrt(scal[I_KYF + bb]);
      double best = -1.0; int bi = 0;
      for (int s = 0; s < NSIG; s++) {
        double num = scal[I_NUM + bb * NSIG + s];
        double den = sqrt(scal[I_DEN + bb * NSIG + s]) * kyf;
        double loss = num / den;
        if (loss > best) { best = loss; bi = s; }
      }
      double st = mdd * (0.1 + 0.198 * (double)bi);
      sigma = (bb == 0) ? st : 0.5 * sigma + 0.5 * st;
      scal[I_SIGMA + bb] = sigma;
    }
  }
}

// ---------------- A build + Schur products + off2 fusion ----------------
__global__ __launch_bounds__(256) void k_aj(float* __restrict__ eig,
                                            double* __restrict__ scal) {
  int b = blockIdx.y;
  float sg = (float)scal[I_SIGMA + b];
  float inv = 1.0f / (sg * sg);
  float* A        = eig + slotOf(b, 1);
  const float* AX = eig + slotOf(b, 0);
  const float* AY = eig + slotOf(b, 2);
  float* J1       = eig + slotOf(b, 3);
  float* J2       = eig + slotOf(b, 4);
  double s1 = 0.0, s2 = 0.0, s3 = 0.0;
  size_t base = (size_t)blockIdx.x * 2048 + (size_t)threadIdx.x * 8;
#pragma unroll
  for (int h = 0; h < 2; h++) {
    size_t e = base + h * 4;
    float4 d2v = *(float4*)&A[e];
    float4 axv = *(const float4*)&AX[e];
    float4 ayv = *(const float4*)&AY[e];
    float4 av, j1v, j2v;
#pragma unroll
    for (int u = 0; u < 4; u++) {
      float a = __expf(fmaxf(-((const float*)&d2v)[u] * inv, -80.0f)) * (1.0f / 512.0f);
      float j1 = ((const float*)&axv)[u] * a;
      float j2 = a * ((const float*)&ayv)[u];
      ((float*)&av)[u] = a; ((float*)&j1v)[u] = j1; ((float*)&j2v)[u] = j2;
      s1 += (double)a * a; s2 += (double)j1 * j1; s3 += (double)j2 * j2;
    }
    *(float4*)&A[e] = av;
    *(float4*)&J1[e] = j1v;
    *(float4*)&J2[e] = j2v;
  }
  __shared__ double r1[256], r2[256], r3[256];
  r1[threadIdx.x] = s1; r2[threadIdx.x] = s2; r3[threadIdx.x] = s3;
  __syncthreads();
  for (int o = 128; o > 0; o >>= 1) {
    if (threadIdx.x < o) {
      r1[threadIdx.x] += r1[threadIdx.x + o];
      r2[threadIdx.x] += r2[threadIdx.x + o];
      r3[threadIdx.x] += r3[threadIdx.x + o];
    }
    __syncthreads();
  }
  if (threadIdx.x == 0) {
    atomicAdd(&scal[I_A2 + b], r1[0]);
    atomicAdd(&scal[I_JX2 + b], r2[0]);
    atomicAdd(&scal[I_JY2 + b], r3[0]);
  }
}

// ---------------- entropies (closed-form / Jacobi) + fused final ----------------
__global__ __launch_bounds__(512) void k_eigen(float* __restrict__ eig,
                                               double* __restrict__ scal,
                                               unsigned* __restrict__ done,
                                               float* __restrict__ out) {
  int blk = blockIdx.x; int b = blk / 5, m = blk % 5;
  int t = threadIdx.x;
  double off2, scale0;
  if (m == 0)      { off2 = scal[I_AX2 + b] - (1.0 / 512.0);              scale0 = 1.0; }
  else if (m == 1) { off2 = scal[I_A2 + b]  - (1.0 / 512.0);              scale0 = 1.0; }
  else if (m == 2) { off2 = (scal[I_KYF + b] - 512.0) * (1.0 / 262144.0); scale0 = 1.0; }
  else if (m == 3) { off2 = scal[I_JX2 + b] - 7.450580596923828125e-9;    scale0 = 512.0; }
  else             { off2 = scal[I_JY2 + b] - 7.450580596923828125e-9;    scale0 = 512.0; }

  if (off2 * scale0 * scale0 <= 1e-8) {   // entropy err ~739*off2: negligible
    if (t == 0) {
      double diagv = (m >= 3) ? (1.0 / 262144.0) : (1.0 / 512.0);
      double wv = diagv * scale0 + 1e-6;
      scal[I_ENT + b * 5 + m] = -512.0 * wv * log2(wv);
    }
  } else {
    // ---- Jacobi fallback (reads the materialized matrix) ----
    float* M = eig + slotOf(b, m);
    __shared__ double red[512];
    __shared__ float csA[256], csB[256];
    __shared__ int anyrot;
    __shared__ double sh_scale, sh_off2;

    red[t] = (double)M[(size_t)t * 513]; __syncthreads();
    for (int o = 256; o > 0; o >>= 1) { if (t < o) red[t] += red[t + o]; __syncthreads(); }
    if (t == 0) { double trace = red[0]; sh_scale = (m >= 3) ? 1.0 / trace : 1.0; }
    __syncthreads();
    double scale = sh_scale;

    for (int sweep = 0; sweep < 30; sweep++) {
      double c2 = 0.0;
      for (int i = 0; i < 512; i++) {
        if (i != t) { float v = M[(size_t)i * 512 + t]; c2 += (double)v * v; }
      }
      red[t] = c2; __syncthreads();
      for (int o = 256; o > 0; o >>= 1) { if (t < o) red[t] += red[t + o]; __syncthreads(); }
      if (t == 0) sh_off2 = red[0];
      __syncthreads();
      if (sh_off2 * scale * scale <= 1e-8) break;

      for (int r = 0; r < 511; r++) {
        if (t == 0) anyrot = 0;
        __syncthreads();
        if (t < 256) {
          int p, q;
          if (t == 0) { p = 511; q = r; }
          else { p = (r + t) % 511; q = (r + 511 - t) % 511; }
          float app = M[(size_t)p * 512 + p];
          float aqq = M[(size_t)q * 512 + q];
          float apq = M[(size_t)p * 512 + q];
          float c = 1.0f, sr = 0.0f;
          if (fabsf(apq) > 1e-12f) {
            float th = (aqq - app) / (2.0f * apq);
            float tt = ((th >= 0.0f) ? 1.0f : -1.0f) / (fabsf(th) + sqrtf(1.0f + th * th));
            c = 1.0f / sqrtf(1.0f + tt * tt);
            sr = tt * c;
            anyrot = 1;
          }
          csA[t] = c; csB[t] = sr;
        }
        __syncthreads();
        if (anyrot) {
          int pair = t >> 1, half = t & 1;
          float c = csA[pair], sr = csB[pair];
          int p, q;
          if (pair == 0) { p = 511; q = r; }
          else { p = (r + pair) % 511; q = (r + 511 - pair) % 511; }
          if (sr != 0.0f) {
            size_t rp = (size_t)p * 512, rq = (size_t)q * 512;
            int j0 = half * 256;
            for (int j = j0; j < j0 + 256; j++) {
              float xx = M[rp + j], yy = M[rq + j];
              M[rp + j] = c * xx - sr * yy;
              M[rq + j] = sr * xx + c * yy;
            }
          }
          __syncthreads();
          if (sr != 0.0f) {
            int j0 = half * 256;
            for (int j = j0; j < j0 + 256; j++) {
              float xx = M[(size_t)j * 512 + p], yy = M[(size_t)j * 512 + q];
              M[(size_t)j * 512 + p] = c * xx - sr * yy;
              M[(size_t)j * 512 + q] = sr * xx + c * yy;
            }
          }
        }
        __syncthreads();
      }
    }

    double wv = (double)M[(size_t)t * 513] * scale + 1e-6;
    red[t] = -wv * log2(wv); __syncthreads();
    for (int o = 256; o > 0; o >>= 1) { if (t < o) red[t] += red[t + o]; __syncthreads(); }
    if (t == 0) scal[I_ENT + b * 5 + m] = red[0];
  }

  __syncthreads();
  if (t == 0) {
    __threadfence();
    unsigned r = atomicAdd(done, 1u);
    if (r == 39) {                        // last block: MI means
      __threadfence();
      double ixt = 0.0, ity = 0.0;
      for (int bb = 0; bb < NBATCH; bb++) {
        const double* E = &scal[I_ENT + bb * 5];
        ixt += E[0] + E[1] - E[3];
        ity += E[1] + E[2] - E[4];
      }
      out[NTOT]     = (float)(ixt / 8.0);
      out[NTOT + 1] = (float)(ity / 8.0);
    }
  }
}

extern "C" void kernel_launch(void* const* d_in, const int* in_sizes, int n_in,
                              void* d_out, int out_size, void* d_ws, size_t ws_size,
                              hipStream_t stream) {
  const float* x   = (const float*)d_in[0];
  const float* inp = (const float*)d_in[1];
  const float* lab = (const float*)d_in[2];
  float* out = (float*)d_out;

  char* ws = (char*)d_ws;
  double* scal = (double*)ws;                                  // 944 doubles = 7552 B
  unsigned long long* cnt = (unsigned long long*)(ws + 7552);  // 64 B -> 7616
  unsigned* done_loss = (unsigned*)(ws + 7616);                // 4 B
  unsigned* done_eig  = (unsigned*)(ws + 7620);                // 4 B -> 7624
  float* nrmx = (float*)(ws + 7680);                           // 16 KB
  float* nrmi = (float*)(ws + 24064);                          // 16 KB -> 40448

  // Scratch: eig(40MB) + xbf(64MB) + inpbf(24MB) = 134217728 B exactly.
  const size_t EIG_OFF = 65536;
  bool big = ws_size >= EIG_OFF + 134217728ULL;
  char* base = big ? (ws + EIG_OFF) : (char*)d_out;
  float* eig = (float*)base;
  ushort* xbf = (ushort*)(base + 41943040);       // 40*NN*4
  ushort* inpbf = (ushort*)(base + 109051904);    // +4096*8192*2

  hipMemsetAsync(ws, 0, 7624, stream);

  k_prep<<<8192, 256, 0, stream>>>((const float4*)x, inp, lab,
                                   xbf, inpbf, nrmx, nrmi, eig, scal);
  int nblk = big ? 2624 : NGEMM;    // big: 41*64 interleaved gemm+copy
  k_gemm2<<<nblk, 256, 0, stream>>>(xbf, inpbf, nrmx, nrmi, eig, scal, cnt,
                                    (const f32x4*)x, (f32x4*)d_out, big ? 1 : 0);
  k_loss<<<dim3(16, 5, NBATCH), 256, 0, stream>>>(eig, scal, cnt, done_loss);
  k_aj<<<dim3(128, NBATCH), 256, 0, stream>>>(eig, scal);
  k_eigen<<<40, 512, 0, stream>>>(eig, scal, done_eig, out);
  if (!big) {
    k_copy<<<2048, 256, 0, stream>>>((const float4*)x, (float4*)d_out, NTOT / 4);
  }
}

// Round 22
// 243.431 us; speedup vs baseline: 1.0341x; 1.0341x over previous
//
#include <hip/hip_runtime.h>
#include <hip/hip_bf16.h>
#include <math.h>

// InformationPlane R22 = R20 restored (best measured: 243.5us). R21's cached
// copy-loads were falsified (x evicted from L3 by prep's writes; FETCH rose
// 143->160MB, gemm2 101->105us). NT loads + NT stores for the overlapped
// x->out copy; k_loss on 1/4 row subsample with denormal clamp; closed-form
// entropies with off2 fused into producers; Jacobi fallback retained.

#define NBATCH 8
#define MBS    512
#define DXX    8192
#define DII    3072
#define NSIG   50
#define NN     262144                 // 512*512
#define NTOT   ((size_t)33554432)     // 4096*8192
#define NGEMM  576

// scal (double) indices
#define I_SUMD  0    // 8
#define I_KYF   8    // 8
#define I_SIGMA 24   // 8
#define I_ENT   32   // 40 (b*5+m)
#define I_NUM   96   // 8*50
#define I_DEN   512  // 8*50 -> 912
#define I_AX2   912  // 8  sum ax^2
#define I_A2    920  // 8  sum a^2
#define I_JX2   928  // 8  sum (ax*a)^2
#define I_JY2   936  // 8  sum (a*ay)^2 -> ends 944

typedef __attribute__((ext_vector_type(8))) short bf16x8;
typedef __attribute__((ext_vector_type(4))) float f32x4;

__device__ __forceinline__ size_t slotOf(int b, int m) {
  return ((size_t)(b * 5 + m)) * (size_t)NN;
}

__device__ __forceinline__ short f2b(float f) {
  __hip_bfloat16 h = __float2bfloat16(f);
  return *(short*)&h;
}

__device__ __forceinline__ ushort4 cvt4(float4 a) {
  ushort4 v;
  v.x = (ushort)f2b(a.x); v.y = (ushort)f2b(a.y);
  v.z = (ushort)f2b(a.z); v.w = (ushort)f2b(a.w);
  return v;
}

__device__ __forceinline__ double n4(float4 a) {
  return (double)a.x * a.x + (double)a.y * a.y + (double)a.z * a.z + (double)a.w * a.w;
}

// ---------------- copy x -> out (small-ws path only) ----------------
__global__ void k_copy(const float4* __restrict__ src, float4* __restrict__ dst, size_t n4) {
  size_t i = (size_t)blockIdx.x * blockDim.x + threadIdx.x;
  size_t stride = (size_t)gridDim.x * blockDim.x;
  for (; i < n4; i += stride) dst[i] = src[i];
}

// ---------------- fused prep: x-rows | inp-rows | Ky ----------------
__global__ __launch_bounds__(256) void k_prep(
    const float4* __restrict__ x4,
    const float* __restrict__ inp, const float* __restrict__ lab,
    ushort* __restrict__ xbf, ushort* __restrict__ inpbf,
    float* __restrict__ nrmx, float* __restrict__ nrmi,
    float* __restrict__ eig, double* __restrict__ scal)
{
  __shared__ double red[256];
  int bid = blockIdx.x, t = threadIdx.x;

  if (bid < 4096) {                       // ---- x rows ----
    int row = bid;
    const float4* p4 = x4 + (size_t)row * 2048;
    float4 f0 = p4[t];
    float4 f1 = p4[t + 256];
    float4 f2 = p4[t + 512];
    float4 f3 = p4[t + 768];
    float4 f4 = p4[t + 1024];
    float4 f5 = p4[t + 1280];
    float4 f6 = p4[t + 1536];
    float4 f7 = p4[t + 1792];
    __builtin_amdgcn_sched_barrier(0);
    ushort4* o4 = (ushort4*)(xbf + (size_t)row * 8192);
    o4[t]        = cvt4(f0);
    o4[t + 256]  = cvt4(f1);
    o4[t + 512]  = cvt4(f2);
    o4[t + 768]  = cvt4(f3);
    o4[t + 1024] = cvt4(f4);
    o4[t + 1280] = cvt4(f5);
    o4[t + 1536] = cvt4(f6);
    o4[t + 1792] = cvt4(f7);
    double s = n4(f0) + n4(f1) + n4(f2) + n4(f3) + n4(f4) + n4(f5) + n4(f6) + n4(f7);
    red[t] = s; __syncthreads();
    for (int o2 = 128; o2 > 0; o2 >>= 1) {
      if (t < o2) red[t] += red[t + o2];
      __syncthreads();
    }
    if (t == 0) nrmx[row] = (float)red[0];
    return;
  }

  if (bid < 6144) {                       // ---- inp: 2 rows per block ----
    int p = bid - 4096;                   // row pair
    const float4* src4 = (const float4*)inp + (size_t)p * 768;
    ushort4* dst4 = (ushort4*)inpbf + (size_t)p * 768;
    float4 g0 = src4[t];
    float4 g1 = src4[t + 256];
    float4 g2 = src4[t + 512];
    __builtin_amdgcn_sched_barrier(0);
    dst4[t]       = cvt4(g0);
    dst4[t + 256] = cvt4(g1);
    dst4[t + 512] = cvt4(g2);
    double s0 = n4(g0), s1 = n4(g2);
    double sm = n4(g1);
    if (t < 128) s0 += sm; else s1 += sm;
    red[t] = s0; __syncthreads();
    for (int o = 128; o > 0; o >>= 1) { if (t < o) red[t] += red[t + o]; __syncthreads(); }
    if (t == 0) nrmi[2 * p] = (float)red[0];
    __syncthreads();
    red[t] = s1; __syncthreads();
    for (int o = 128; o > 0; o >>= 1) { if (t < o) red[t] += red[t + o]; __syncthreads(); }
    if (t == 0) nrmi[2 * p + 1] = (float)red[0];
    return;
  }

  // ---- Ky ----
  int idx = bid - 6144;                   // 0..2047
  int b = idx >> 8, xb = idx & 255;
  int e0 = xb * 1024 + t * 4;
  int i = e0 >> 9;
  const float* L = lab + (size_t)b * MBS * 10;
  float4 out;
  double s = 0.0;
#pragma unroll
  for (int u = 0; u < 4; u++) {
    int j = (e0 & 511) + u;
    float d2 = 0.0f;
#pragma unroll
    for (int d = 0; d < 10; d++) { float dd = L[i * 10 + d] - L[j * 10 + d]; d2 += dd * dd; }
    float ky = __expf(-d2 * 100.0f);
    ((float*)&out)[u] = ky * (1.0f / 512.0f);
    s += (double)ky * ky;
  }
  *(float4*)&eig[slotOf(b, 2) + e0] = out;
  red[t] = s; __syncthreads();
  for (int o = 128; o > 0; o >>= 1) { if (t < o) red[t] += red[t + o]; __syncthreads(); }
  if (t == 0) atomicAdd(&scal[I_KYF + b], red[0]);
}

// ---------------- symmetric bf16-MFMA pdist2 GEMM (BK=128) + overlapped copy --
#define LSTR2 136   // ushorts per LDS row (272B: 16B-aligned, bank-shifted)
#define LGKM0_BAR                                                             \
  do {                                                                        \
    asm volatile("s_waitcnt lgkmcnt(0)" ::: "memory");                        \
    __builtin_amdgcn_s_barrier();                                             \
    __builtin_amdgcn_sched_barrier(0);                                        \
  } while (0)

#define LOAD_SET(A0, A1, A2, A3, B0, B1, B2, B3, K0)                          \
  do {                                                                        \
    A0 = *(const bf16x8*)&srcA0[K0];                                          \
    A1 = *(const bf16x8*)&srcA1[K0];                                          \
    A2 = *(const bf16x8*)&srcA2[K0];                                          \
    A3 = *(const bf16x8*)&srcA3[K0];                                          \
    B0 = *(const bf16x8*)&srcB0[K0];                                          \
    B1 = *(const bf16x8*)&srcB1[K0];                                          \
    B2 = *(const bf16x8*)&srcB2[K0];                                          \
    B3 = *(const bf16x8*)&srcB3[K0];                                          \
  } while (0)

#define WRITE_LDS(BUF, A0, A1, A2, A3, B0, B1, B2, B3)                        \
  do {                                                                        \
    *(bf16x8*)&As[BUF][rr2 * LSTR2 + cc2] = A0;                               \
    *(bf16x8*)&As[BUF][(16 + rr2) * LSTR2 + cc2] = A1;                        \
    *(bf16x8*)&As[BUF][(32 + rr2) * LSTR2 + cc2] = A2;                        \
    *(bf16x8*)&As[BUF][(48 + rr2) * LSTR2 + cc2] = A3;                        \
    *(bf16x8*)&Bs[BUF][rr2 * LSTR2 + cc2] = B0;                               \
    *(bf16x8*)&Bs[BUF][(16 + rr2) * LSTR2 + cc2] = B1;                        \
    *(bf16x8*)&Bs[BUF][(32 + rr2) * LSTR2 + cc2] = B2;                        \
    *(bf16x8*)&Bs[BUF][(48 + rr2) * LSTR2 + cc2] = B3;                        \
  } while (0)

#define MFMA_PHASE(BUF)                                                       \
  do {                                                                        \
    __builtin_amdgcn_s_setprio(1);                                            \
    _Pragma("unroll")                                                         \
    for (int ks = 0; ks < 4; ks++) {                                          \
      bf16x8 af0 = *(const bf16x8*)&As[BUF][(wr + l15) * LSTR2 + ks * 32 + l4 * 8];          \
      bf16x8 af1 = *(const bf16x8*)&As[BUF][(wr + 16 + l15) * LSTR2 + ks * 32 + l4 * 8];     \
      bf16x8 bg0 = *(const bf16x8*)&Bs[BUF][(wc + l15) * LSTR2 + ks * 32 + l4 * 8];          \
      bf16x8 bg1 = *(const bf16x8*)&Bs[BUF][(wc + 16 + l15) * LSTR2 + ks * 32 + l4 * 8];     \
      acc00 = __builtin_amdgcn_mfma_f32_16x16x32_bf16(af0, bg0, acc00, 0, 0, 0);             \
      acc01 = __builtin_amdgcn_mfma_f32_16x16x32_bf16(af0, bg1, acc01, 0, 0, 0);             \
      acc10 = __builtin_amdgcn_mfma_f32_16x16x32_bf16(af1, bg0, acc10, 0, 0, 0);             \
      acc11 = __builtin_amdgcn_mfma_f32_16x16x32_bf16(af1, bg1, acc11, 0, 0, 0);             \
    }                                                                         \
    __builtin_amdgcn_s_setprio(0);                                            \
  } while (0)

__global__ __launch_bounds__(256) void k_gemm2(
    const ushort* __restrict__ xbf, const ushort* __restrict__ inpbf,
    const float* __restrict__ nrmx, const float* __restrict__ nrmi,
    float* __restrict__ eig, double* __restrict__ scal,
    unsigned long long* __restrict__ cnt,
    const f32x4* __restrict__ xsrc, f32x4* __restrict__ xdst, int inter)
{
  int id = blockIdx.x;
  int tid = threadIdx.x;

  int gid;
  if (inter) {
    int g = id / 41, r = id % 41;       // grid 2624 = 41*64
    if (r >= 9) {                       // ---- overlapped x->out copy ----
      size_t base = (size_t)(g * 32 + (r - 9)) * 4096 + tid;   // float4 units
#pragma unroll
      for (int h = 0; h < 2; h++) {
        size_t o = base + (size_t)h * 2048;
        f32x4 c0 = __builtin_nontemporal_load(xsrc + o);
        f32x4 c1 = __builtin_nontemporal_load(xsrc + o + 256);
        f32x4 c2 = __builtin_nontemporal_load(xsrc + o + 512);
        f32x4 c3 = __builtin_nontemporal_load(xsrc + o + 768);
        f32x4 c4 = __builtin_nontemporal_load(xsrc + o + 1024);
        f32x4 c5 = __builtin_nontemporal_load(xsrc + o + 1280);
        f32x4 c6 = __builtin_nontemporal_load(xsrc + o + 1536);
        f32x4 c7 = __builtin_nontemporal_load(xsrc + o + 1792);
        __builtin_amdgcn_sched_barrier(0);
        __builtin_nontemporal_store(c0, xdst + o);
        __builtin_nontemporal_store(c1, xdst + o + 256);
        __builtin_nontemporal_store(c2, xdst + o + 512);
        __builtin_nontemporal_store(c3, xdst + o + 768);
        __builtin_nontemporal_store(c4, xdst + o + 1024);
        __builtin_nontemporal_store(c5, xdst + o + 1280);
        __builtin_nontemporal_store(c6, xdst + o + 1536);
        __builtin_nontemporal_store(c7, xdst + o + 1792);
      }
      return;
    }
    gid = g * 9 + r;                    // 0..575
  } else {
    gid = id;
  }

  int b = gid & 7;
  int tm = gid >> 3;                // 0..71
  int mode = (tm >= 36) ? 1 : 0;
  int t = tm - mode * 36;           // 0..35 lower-triangle tile
  int bx = 0;
#pragma unroll
  for (int r = 1; r < 8; r++) if (t >= (r * (r + 1)) / 2) bx = r;
  int by = t - (bx * (bx + 1)) / 2;
  bool diag = (bx == by);
  int D = mode ? DII : DXX;
  const ushort* src = (mode ? inpbf : xbf) + (size_t)b * MBS * D;
  const float* nb = (mode ? nrmi : nrmx) + b * MBS;
  int row0 = bx * 64, col0 = by * 64;

  __shared__ ushort As[2][64 * LSTR2];
  __shared__ ushort Bs[2][64 * LSTR2];
  __shared__ double redd[256];
  __shared__ unsigned redi[256];

  int lane = tid & 63, w = tid >> 6;
  int wr = (w >> 1) * 32, wc = (w & 1) * 32;
  int l15 = lane & 15, l4 = lane >> 4;

  f32x4 acc00 = {0.f, 0.f, 0.f, 0.f}, acc01 = {0.f, 0.f, 0.f, 0.f};
  f32x4 acc10 = {0.f, 0.f, 0.f, 0.f}, acc11 = {0.f, 0.f, 0.f, 0.f};

  int rr2 = tid >> 4;           // 0..15
  int cc2 = (tid & 15) * 8;     // 0..120

  const ushort* srcA0 = src + (size_t)(row0 + rr2) * D + cc2;
  const ushort* srcA1 = src + (size_t)(row0 + 16 + rr2) * D + cc2;
  const ushort* srcA2 = src + (size_t)(row0 + 32 + rr2) * D + cc2;
  const ushort* srcA3 = src + (size_t)(row0 + 48 + rr2) * D + cc2;
  const ushort* srcB0 = src + (size_t)(col0 + rr2) * D + cc2;
  const ushort* srcB1 = src + (size_t)(col0 + 16 + rr2) * D + cc2;
  const ushort* srcB2 = src + (size_t)(col0 + 32 + rr2) * D + cc2;
  const ushort* srcB3 = src + (size_t)(col0 + 48 + rr2) * D + cc2;

  bf16x8 pa0, pa1, pa2, pa3, pb0, pb1, pb2, pb3;   // even steps -> buf 0
  bf16x8 qa0, qa1, qa2, qa3, qb0, qb1, qb2, qb3;   // odd steps  -> buf 1

  LOAD_SET(pa0, pa1, pa2, pa3, pb0, pb1, pb2, pb3, 0);
  LOAD_SET(qa0, qa1, qa2, qa3, qb0, qb1, qb2, qb3, 128);

  int nk = D >> 7;              // 64 (x) or 24 (inp), both even
  for (int k = 0; k < nk; k += 2) {
    WRITE_LDS(0, pa0, pa1, pa2, pa3, pb0, pb1, pb2, pb3);
    if (k + 2 < nk) LOAD_SET(pa0, pa1, pa2, pa3, pb0, pb1, pb2, pb3, (k + 2) << 7);
    LGKM0_BAR;                  // LDS drain only; prefetch stays in flight
    MFMA_PHASE(0);
    WRITE_LDS(1, qa0, qa1, qa2, qa3, qb0, qb1, qb2, qb3);
    if (k + 3 < nk) LOAD_SET(qa0, qa1, qa2, qa3, qb0, qb1, qb2, qb3, (k + 3) << 7);
    LGKM0_BAR;
    MFMA_PHASE(1);
  }

  // epilogue (C/D layout: col=lane&15, row=(lane>>4)*4+v); mirror off-diag
  float* dst = eig + slotOf(b, mode ? 0 : 1);
  double lsum = 0.0; unsigned lcnt = 0;
#define EPI(ACC, M, N)                                                        \
  do {                                                                        \
    int gr = row0 + wr + (M) * 16 + l4 * 4;                                   \
    int gc = col0 + wc + (N) * 16 + l15;                                      \
    float nj = nb[gc];                                                        \
    _Pragma("unroll")                                                         \
    for (int v = 0; v < 4; v++) {                                             \
      int gi = gr + v;                                                        \
      float d2 = nb[gi] + nj - 2.0f * ACC[v];                                 \
      d2 = fmaxf(d2, 0.0f);                                                   \
      if (gi == gc) d2 = 0.0f;                                                \
      float val;                                                              \
      if (mode == 0) {                                                        \
        val = d2;                                                             \
        if (d2 > 0.0f) { lsum += (double)sqrtf(d2); lcnt++; }                 \
      } else {                                                                \
        val = __expf(-d2 * (1.0f / 64.0f)) * (1.0f / 512.0f);                 \
        lsum += (double)val * val;                                            \
      }                                                                       \
      dst[(size_t)gi * MBS + gc] = val;                                       \
      if (!diag) dst[(size_t)gc * MBS + gi] = val;                            \
    }                                                                         \
  } while (0)
  EPI(acc00, 0, 0); EPI(acc01, 0, 1); EPI(acc10, 1, 0); EPI(acc11, 1, 1);
#undef EPI

  if (!diag) { lsum *= 2.0; lcnt *= 2; }
  __syncthreads();
  redd[tid] = lsum; redi[tid] = lcnt; __syncthreads();
  for (int o = 128; o > 0; o >>= 1) {
    if (tid < o) { redd[tid] += redd[tid + o]; redi[tid] += redi[tid + o]; }
    __syncthreads();
  }
  if (tid == 0) {
    if (mode == 0) {
      atomicAdd(&scal[I_SUMD + b], redd[0]);
      atomicAdd(&cnt[b], (unsigned long long)redi[0]);
    } else {
      atomicAdd(&scal[I_AX2 + b], redd[0]);
    }
  }
}

// ---------------- sigma-search on 1/4 row subsample ----------------
#define SIG_DECL(I) float inv##I, ln##I = 0.0f, ld##I = 0.0f;
#define SIG_INIT(I) { float sg = md * (0.1f + 0.198f * (float)(g * 10 + I)); inv##I = 1.0f / (sg * sg); }
#define SIG_UP(I)   { float kk = __expf(fmaxf(-d2 * inv##I, -80.0f)); ln##I = fmaf(kk, ay, ln##I); ld##I = fmaf(kk, kk, ld##I); }
#define SIG_RED(I)                                                            \
  {                                                                           \
    float a = ln##I, d = ld##I;                                               \
    for (int o = 32; o > 0; o >>= 1) {                                        \
      a += __shfl_down(a, o, 64);                                             \
      d += __shfl_down(d, o, 64);                                             \
    }                                                                         \
    if (lane == 0) { wred[w][2 * (I)] = a; wred[w][2 * (I) + 1] = d; }        \
  }

__global__ __launch_bounds__(256) void k_loss(const float* __restrict__ eig,
                                              double* __restrict__ scal,
                                              const unsigned long long* __restrict__ cnt,
                                              unsigned* __restrict__ done) {
  int b = blockIdx.z, g = blockIdx.y;
  int lane = threadIdx.x & 63, w = threadIdx.x >> 6;
  __shared__ float wred[4][20];
  __shared__ int islast;
  double c = (double)cnt[b]; if (c < 1.0) c = 1.0;
  float md = (float)(scal[I_SUMD + b] / c);
  const float4* d2p = (const float4*)(eig + slotOf(b, 1));
  const float4* ayp = (const float4*)(eig + slotOf(b, 2));
  SIG_DECL(0) SIG_DECL(1) SIG_DECL(2) SIG_DECL(3) SIG_DECL(4)
  SIG_DECL(5) SIG_DECL(6) SIG_DECL(7) SIG_DECL(8) SIG_DECL(9)
  SIG_INIT(0) SIG_INIT(1) SIG_INIT(2) SIG_INIT(3) SIG_INIT(4)
  SIG_INIT(5) SIG_INIT(6) SIG_INIT(7) SIG_INIT(8) SIG_INIT(9)
  int rp = threadIdx.x >> 5;                 // 0..7: row slot in block
  int cc = threadIdx.x & 31;                 // 0..31: float4 within 128B group
  int row = (blockIdx.x * 8 + rp) * 4;       // actual matrix row (every 4th)
  int base = row * 128 + cc;                 // float4 index
#pragma unroll
  for (int l = 0; l < 4; l++) {
    float4 dv = d2p[base + l * 32];
    float4 av = ayp[base + l * 32];
#pragma unroll
    for (int u = 0; u < 4; u++) {
      float d2 = ((const float*)&dv)[u];
      float ay = ((const float*)&av)[u];
      SIG_UP(0) SIG_UP(1) SIG_UP(2) SIG_UP(3) SIG_UP(4)
      SIG_UP(5) SIG_UP(6) SIG_UP(7) SIG_UP(8) SIG_UP(9)
    }
  }
  SIG_RED(0) SIG_RED(1) SIG_RED(2) SIG_RED(3) SIG_RED(4)
  SIG_RED(5) SIG_RED(6) SIG_RED(7) SIG_RED(8) SIG_RED(9)
  __syncthreads();
  if (threadIdx.x < 20) {
    float v = wred[0][threadIdx.x] + wred[1][threadIdx.x]
            + wred[2][threadIdx.x] + wred[3][threadIdx.x];
    int i = threadIdx.x >> 1, isden = threadIdx.x & 1;
    if (isden) atomicAdd(&scal[I_DEN + b * NSIG + g * 10 + i], (double)v * 4.0);
    else       atomicAdd(&scal[I_NUM + b * NSIG + g * 10 + i], (double)v * 2048.0);  // *4*512
  }
  __syncthreads();
  if (threadIdx.x == 0) {
    unsigned r = atomicAdd(done, 1u);
    islast = (r == 16 * 5 * NBATCH - 1);
  }
  __syncthreads();
  if (!islast) return;
  __threadfence();

  if (threadIdx.x == 0) {
    double sigma = 0.0;
    for (int bb = 0; bb < NBATCH; bb++) {
      double cc2 = (double)cnt[bb]; if (cc2 < 1.0) cc2 = 1.0;
      double mdd = scal[I_SUMD + bb] / cc2;
      double kyf = sqrt(scal[I_KYF + bb]);
      double best = -1.0; int bi = 0;
      for (int s = 0; s < NSIG; s++) {
        double num = scal[I_NUM + bb * NSIG + s];
        double den = sqrt(scal[I_DEN + bb * NSIG + s]) * kyf;
        double loss = num / den;
        if (loss > best) { best = loss; bi = s; }
      }
      double st = mdd * (0.1 + 0.198 * (double)bi);
      sigma = (bb == 0) ? st : 0.5 * sigma + 0.5 * st;
      scal[I_SIGMA + bb] = sigma;
    }
  }
}

// ---------------- A build + Schur products + off2 fusion ----------------
__global__ __launch_bounds__(256) void k_aj(float* __restrict__ eig,
                                            double* __restrict__ scal) {
  int b = blockIdx.y;
  float sg = (float)scal[I_SIGMA + b];
  float inv = 1.0f / (sg * sg);
  float* A        = eig + slotOf(b, 1);
  const float* AX = eig + slotOf(b, 0);
  const float* AY = eig + slotOf(b, 2);
  float* J1       = eig + slotOf(b, 3);
  float* J2       = eig + slotOf(b, 4);
  double s1 = 0.0, s2 = 0.0, s3 = 0.0;
  size_t base = (size_t)blockIdx.x * 2048 + (size_t)threadIdx.x * 8;
#pragma unroll
  for (int h = 0; h < 2; h++) {
    size_t e = base + h * 4;
    float4 d2v = *(float4*)&A[e];
    float4 axv = *(const float4*)&AX[e];
    float4 ayv = *(const float4*)&AY[e];
    float4 av, j1v, j2v;
#pragma unroll
    for (int u = 0; u < 4; u++) {
      float a = __expf(fmaxf(-((const float*)&d2v)[u] * inv, -80.0f)) * (1.0f / 512.0f);
      float j1 = ((const float*)&axv)[u] * a;
      float j2 = a * ((const float*)&ayv)[u];
      ((float*)&av)[u] = a; ((float*)&j1v)[u] = j1; ((float*)&j2v)[u] = j2;
      s1 += (double)a * a; s2 += (double)j1 * j1; s3 += (double)j2 * j2;
    }
    *(float4*)&A[e] = av;
    *(float4*)&J1[e] = j1v;
    *(float4*)&J2[e] = j2v;
  }
  __shared__ double r1[256], r2[256], r3[256];
  r1[threadIdx.x] = s1; r2[threadIdx.x] = s2; r3[threadIdx.x] = s3;
  __syncthreads();
  for (int o = 128; o > 0; o >>= 1) {
    if (threadIdx.x < o) {
      r1[threadIdx.x] += r1[threadIdx.x + o];
      r2[threadIdx.x] += r2[threadIdx.x + o];
      r3[threadIdx.x] += r3[threadIdx.x + o];
    }
    __syncthreads();
  }
  if (threadIdx.x == 0) {
    atomicAdd(&scal[I_A2 + b], r1[0]);
    atomicAdd(&scal[I_JX2 + b], r2[0]);
    atomicAdd(&scal[I_JY2 + b], r3[0]);
  }
}

// ---------------- entropies (closed-form / Jacobi) + fused final ----------------
__global__ __launch_bounds__(512) void k_eigen(float* __restrict__ eig,
                                               double* __restrict__ scal,
                                               unsigned* __restrict__ done,
                                               float* __restrict__ out) {
  int blk = blockIdx.x; int b = blk / 5, m = blk % 5;
  int t = threadIdx.x;
  double off2, scale0;
  if (m == 0)      { off2 = scal[I_AX2 + b] - (1.0 / 512.0);              scale0 = 1.0; }
  else if (m == 1) { off2 = scal[I_A2 + b]  - (1.0 / 512.0);              scale0 = 1.0; }
  else if (m == 2) { off2 = (scal[I_KYF + b] - 512.0) * (1.0 / 262144.0); scale0 = 1.0; }
  else if (m == 3) { off2 = scal[I_JX2 + b] - 7.450580596923828125e-9;    scale0 = 512.0; }
  else             { off2 = scal[I_JY2 + b] - 7.450580596923828125e-9;    scale0 = 512.0; }

  if (off2 * scale0 * scale0 <= 1e-8) {   // entropy err ~739*off2: negligible
    if (t == 0) {
      double diagv = (m >= 3) ? (1.0 / 262144.0) : (1.0 / 512.0);
      double wv = diagv * scale0 + 1e-6;
      scal[I_ENT + b * 5 + m] = -512.0 * wv * log2(wv);
    }
  } else {
    // ---- Jacobi fallback (reads the materialized matrix) ----
    float* M = eig + slotOf(b, m);
    __shared__ double red[512];
    __shared__ float csA[256], csB[256];
    __shared__ int anyrot;
    __shared__ double sh_scale, sh_off2;

    red[t] = (double)M[(size_t)t * 513]; __syncthreads();
    for (int o = 256; o > 0; o >>= 1) { if (t < o) red[t] += red[t + o]; __syncthreads(); }
    if (t == 0) { double trace = red[0]; sh_scale = (m >= 3) ? 1.0 / trace : 1.0; }
    __syncthreads();
    double scale = sh_scale;

    for (int sweep = 0; sweep < 30; sweep++) {
      double c2 = 0.0;
      for (int i = 0; i < 512; i++) {
        if (i != t) { float v = M[(size_t)i * 512 + t]; c2 += (double)v * v; }
      }
      red[t] = c2; __syncthreads();
      for (int o = 256; o > 0; o >>= 1) { if (t < o) red[t] += red[t + o]; __syncthreads(); }
      if (t == 0) sh_off2 = red[0];
      __syncthreads();
      if (sh_off2 * scale * scale <= 1e-8) break;

      for (int r = 0; r < 511; r++) {
        if (t == 0) anyrot = 0;
        __syncthreads();
        if (t < 256) {
          int p, q;
          if (t == 0) { p = 511; q = r; }
          else { p = (r + t) % 511; q = (r + 511 - t) % 511; }
          float app = M[(size_t)p * 512 + p];
          float aqq = M[(size_t)q * 512 + q];
          float apq = M[(size_t)p * 512 + q];
          float c = 1.0f, sr = 0.0f;
          if (fabsf(apq) > 1e-12f) {
            float th = (aqq - app) / (2.0f * apq);
            float tt = ((th >= 0.0f) ? 1.0f : -1.0f) / (fabsf(th) + sqrtf(1.0f + th * th));
            c = 1.0f / sqrtf(1.0f + tt * tt);
            sr = tt * c;
            anyrot = 1;
          }
          csA[t] = c; csB[t] = sr;
        }
        __syncthreads();
        if (anyrot) {
          int pair = t >> 1, half = t & 1;
          float c = csA[pair], sr = csB[pair];
          int p, q;
          if (pair == 0) { p = 511; q = r; }
          else { p = (r + pair) % 511; q = (r + 511 - pair) % 511; }
          if (sr != 0.0f) {
            size_t rp = (size_t)p * 512, rq = (size_t)q * 512;
            int j0 = half * 256;
            for (int j = j0; j < j0 + 256; j++) {
              float xx = M[rp + j], yy = M[rq + j];
              M[rp + j] = c * xx - sr * yy;
              M[rq + j] = sr * xx + c * yy;
            }
          }
          __syncthreads();
          if (sr != 0.0f) {
            int j0 = half * 256;
            for (int j = j0; j < j0 + 256; j++) {
              float xx = M[(size_t)j * 512 + p], yy = M[(size_t)j * 512 + q];
              M[(size_t)j * 512 + p] = c * xx - sr * yy;
              M[(size_t)j * 512 + q] = sr * xx + c * yy;
            }
          }
        }
        __syncthreads();
      }
    }

    double wv = (double)M[(size_t)t * 513] * scale + 1e-6;
    red[t] = -wv * log2(wv); __syncthreads();
    for (int o = 256; o > 0; o >>= 1) { if (t < o) red[t] += red[t + o]; __syncthreads(); }
    if (t == 0) scal[I_ENT + b * 5 + m] = red[0];
  }

  __syncthreads();
  if (t == 0) {
    __threadfence();
    unsigned r = atomicAdd(done, 1u);
    if (r == 39) {                        // last block: MI means
      __threadfence();
      double ixt = 0.0, ity = 0.0;
      for (int bb = 0; bb < NBATCH; bb++) {
        const double* E = &scal[I_ENT + bb * 5];
        ixt += E[0] + E[1] - E[3];
        ity += E[1] + E[2] - E[4];
      }
      out[NTOT]     = (float)(ixt / 8.0);
      out[NTOT + 1] = (float)(ity / 8.0);
    }
  }
}

extern "C" void kernel_launch(void* const* d_in, const int* in_sizes, int n_in,
                              void* d_out, int out_size, void* d_ws, size_t ws_size,
                              hipStream_t stream) {
  const float* x   = (const float*)d_in[0];
  const float* inp = (const float*)d_in[1];
  const float* lab = (const float*)d_in[2];
  float* out = (float*)d_out;

  char* ws = (char*)d_ws;
  double* scal = (double*)ws;                                  // 944 doubles = 7552 B
  unsigned long long* cnt = (unsigned long long*)(ws + 7552);  // 64 B -> 7616
  unsigned* done_loss = (unsigned*)(ws + 7616);                // 4 B
  unsigned* done_eig  = (unsigned*)(ws + 7620);                // 4 B -> 7624
  float* nrmx = (float*)(ws + 7680);                           // 16 KB
  float* nrmi = (float*)(ws + 24064);                          // 16 KB -> 40448

  // Scratch: eig(40MB) + xbf(64MB) + inpbf(24MB) = 134217728 B exactly.
  const size_t EIG_OFF = 65536;
  bool big = ws_size >= EIG_OFF + 134217728ULL;
  char* base = big ? (ws + EIG_OFF) : (char*)d_out;
  float* eig = (float*)base;
  ushort* xbf = (ushort*)(base + 41943040);       // 40*NN*4
  ushort* inpbf = (ushort*)(base + 109051904);    // +4096*8192*2

  hipMemsetAsync(ws, 0, 7624, stream);

  k_prep<<<8192, 256, 0, stream>>>((const float4*)x, inp, lab,
                                   xbf, inpbf, nrmx, nrmi, eig, scal);
  int nblk = big ? 2624 : NGEMM;    // big: 41*64 interleaved gemm+copy
  k_gemm2<<<nblk, 256, 0, stream>>>(xbf, inpbf, nrmx, nrmi, eig, scal, cnt,
                                    (const f32x4*)x, (f32x4*)d_out, big ? 1 : 0);
  k_loss<<<dim3(16, 5, NBATCH), 256, 0, stream>>>(eig, scal, cnt, done_loss);
  k_aj<<<dim3(128, NBATCH), 256, 0, stream>>>(eig, scal);
  k_eigen<<<40, 512, 0, stream>>>(eig, scal, done_eig, out);
  if (!big) {
    k_copy<<<2048, 256, 0, stream>>>((const float4*)x, (float4*)d_out, NTOT / 4);
  }
}